// Round 1
// baseline (23265.938 us; speedup 1.0000x reference)
//
#include <hip/hip_runtime.h>
#include <cstdint>
#include <cstddef>
#include <cmath>

#define D 256
#define H 4
#define DK 64
#define LN_EPS 1e-5f

// ---------------- QKV projection: one block per (b,s) row ----------------
__global__ void qkv_kernel(const float* __restrict__ x,
                           const float* __restrict__ Wq,
                           const float* __restrict__ Wk,
                           const float* __restrict__ Wv,
                           float* __restrict__ q, float* __restrict__ k,
                           float* __restrict__ v)
{
    const int row = blockIdx.x;
    const int j = threadIdx.x;          // 256 threads
    __shared__ float xs[D];
    const size_t base = (size_t)row * D;
    xs[j] = x[base + j];
    __syncthreads();
    float aq = 0.f, ak = 0.f, av = 0.f;
    #pragma unroll 8
    for (int i = 0; i < D; ++i) {
        const float xv = xs[i];
        aq = fmaf(xv, Wq[i*D + j], aq);
        ak = fmaf(xv, Wk[i*D + j], ak);
        av = fmaf(xv, Wv[i*D + j], av);
    }
    q[base + j] = aq; k[base + j] = ak; v[base + j] = av;
}

// ---------------- Attention: one block per (b,h,query) ----------------
// out may alias q: the block reads only its own q slice (before writing it).
__global__ void attn_kernel(const float* __restrict__ q,
                            const float* __restrict__ k,
                            const float* __restrict__ v,
                            const float* __restrict__ attn_w_l, // [H,6]
                            const int* __restrict__ Kp,
                            float* __restrict__ out, int S)
{
    const int qi = blockIdx.x, h = blockIdx.y, b = blockIdx.z;
    const int tid = threadIdx.x;  // 256
    __shared__ float qs[DK];
    __shared__ float kt[64][DK + 1];
    __shared__ float sc[512];
    __shared__ float red[256];
    __shared__ float gates[6];
    const int NK = S - 1;
    const int Kc = Kp[0];
    if (tid < 6) gates[tid] = tanhf(attn_w_l[h*6 + tid]);
    const size_t rowbase = ((size_t)b * S + qi) * D + (size_t)h * DK;
    if (tid < DK) qs[tid] = q[rowbase + tid];
    for (int i = tid; i < 512; i += 256) sc[i] = -INFINITY;
    __syncthreads();

    const size_t kvbase = (size_t)b * S * D + (size_t)h * DK;
    const int ntile = (S + 63) >> 6;
    for (int t = 0; t < ntile; ++t) {
        const int k0 = t << 6;
        for (int e = tid; e < 64 * DK; e += 256) {
            const int kk = e >> 6, i = e & 63;
            const int kg = k0 + kk;
            kt[kk][i] = (kg < S) ? k[kvbase + (size_t)kg * D + i] : 0.f;
        }
        __syncthreads();
        if (tid < 64) {
            const int kg = k0 + tid;
            if (kg < S) {
                float acc = 0.f;
                #pragma unroll
                for (int i = 0; i < DK; ++i) acc = fmaf(qs[i], kt[tid][i], acc);
                sc[kg] = acc * 0.125f;     // / sqrt(DK)
            }
        }
        __syncthreads();
    }

    // row max
    float m = -INFINITY;
    for (int i = tid; i < 512; i += 256) m = fmaxf(m, sc[i]);
    red[tid] = m; __syncthreads();
    for (int s = 128; s > 0; s >>= 1) {
        if (tid < s) red[tid] = fmaxf(red[tid], red[tid + s]);
        __syncthreads();
    }
    m = red[0];
    __syncthreads();

    // exp + sum (sum over UN-gated probabilities, per reference)
    float ps = 0.f;
    for (int i = tid; i < S; i += 256) {
        const float e = __expf(sc[i] - m);
        sc[i] = e; ps += e;
    }
    red[tid] = ps; __syncthreads();
    for (int s = 128; s > 0; s >>= 1) {
        if (tid < s) red[tid] += red[tid + s];
        __syncthreads();
    }
    const float inv = 1.0f / red[0];
    __syncthreads();

    // apply tanh gate (category matrix computed on the fly)
    const int qcls = (qi < NK) ? (qi / Kc) : 0;
    for (int i = tid; i < S; i += 256) {
        int cat;
        if (qi < NK) {
            if (i == NK)      cat = 3;                         // s -> query col
            else if (i == qi) cat = 0;                         // same sample
            else              cat = ((i / Kc) == qcls) ? 1 : 2; // same/diff class
        } else {
            cat = (i < NK) ? 4 : 5;                            // query row
        }
        sc[i] *= gates[cat];
    }
    __syncthreads();

    // out[d] = inv * sum_k sc[k]*v[k,d]; thread = d + 64*g
    const int d = tid & 63, g = tid >> 6;
    float acc = 0.f;
    for (int kk = g; kk < S; kk += 4)
        acc = fmaf(sc[kk], v[kvbase + (size_t)kk * D + d], acc);
    red[tid] = acc; __syncthreads();
    if (tid < 64) {
        const float o = (red[tid] + red[tid + 64] + red[tid + 128] + red[tid + 192]) * inv;
        out[rowbase + tid] = o;
    }
}

// ---------------- FC + residual + LayerNorm: one block per row ----------------
// out may alias tin and/or resid (all row-local).
__global__ void fc_res_ln_kernel(const float* __restrict__ tin,
                                 const float* __restrict__ W,
                                 const float* __restrict__ bias,
                                 const float* __restrict__ resid,
                                 const float* __restrict__ gam,
                                 const float* __restrict__ bet,
                                 float* __restrict__ out)
{
    const int row = blockIdx.x, j = threadIdx.x;
    __shared__ float ts[D];
    __shared__ float red[D];
    const size_t base = (size_t)row * D;
    ts[j] = tin[base + j];
    __syncthreads();
    float acc = 0.f;
    #pragma unroll 8
    for (int i = 0; i < D; ++i) acc = fmaf(ts[i], W[i*D + j], acc);
    const float val = acc + bias[j] + resid[base + j];

    red[j] = val; __syncthreads();
    for (int s = 128; s > 0; s >>= 1) { if (j < s) red[j] += red[j + s]; __syncthreads(); }
    const float mu = red[0] * (1.f / D);
    __syncthreads();
    const float dv = val - mu;
    red[j] = dv * dv; __syncthreads();
    for (int s = 128; s > 0; s >>= 1) { if (j < s) red[j] += red[j + s]; __syncthreads(); }
    const float var = red[0] * (1.f / D);
    out[base + j] = dv * rsqrtf(var + LN_EPS) * gam[j] + bet[j];
}

// ---------------- Fused FFN (relu) + residual + LayerNorm, in-place on x ----------------
__global__ void ffn_ln_kernel(const float* __restrict__ W1, const float* __restrict__ b1,
                              const float* __restrict__ W2, const float* __restrict__ b2,
                              float* __restrict__ x,
                              const float* __restrict__ gam, const float* __restrict__ bet)
{
    const int row = blockIdx.x, j = threadIdx.x;
    __shared__ float xs[D];
    __shared__ float hs[D];
    __shared__ float red[D];
    const size_t base = (size_t)row * D;
    const float xv = x[base + j];
    xs[j] = xv;
    __syncthreads();
    float acc = 0.f;
    #pragma unroll 8
    for (int i = 0; i < D; ++i) acc = fmaf(xs[i], W1[i*D + j], acc);
    const float hv = fmaxf(acc + b1[j], 0.f);
    hs[j] = hv;
    __syncthreads();
    acc = 0.f;
    #pragma unroll 8
    for (int i = 0; i < D; ++i) acc = fmaf(hs[i], W2[i*D + j], acc);
    const float val = acc + b2[j] + xv;

    red[j] = val; __syncthreads();
    for (int s = 128; s > 0; s >>= 1) { if (j < s) red[j] += red[j + s]; __syncthreads(); }
    const float mu = red[0] * (1.f / D);
    __syncthreads();
    const float dv = val - mu;
    red[j] = dv * dv; __syncthreads();
    for (int s = 128; s > 0; s >>= 1) { if (j < s) red[j] += red[j + s]; __syncthreads(); }
    const float var = red[0] * (1.f / D);
    x[base + j] = dv * rsqrtf(var + LN_EPS) * gam[j] + bet[j];
}

extern "C" void kernel_launch(void* const* d_in, const int* in_sizes, int n_in,
                              void* d_out, int out_size, void* d_ws, size_t ws_size,
                              hipStream_t stream)
{
    const float* samples = (const float*)d_in[0];
    const float* Wq      = (const float*)d_in[1];
    const float* Wk      = (const float*)d_in[2];
    const float* Wv      = (const float*)d_in[3];
    const float* attn_w  = (const float*)d_in[4];
    const float* fc_w    = (const float*)d_in[5];
    const float* fc_b    = (const float*)d_in[6];
    const float* mha_g   = (const float*)d_in[7];
    const float* mha_b   = (const float*)d_in[8];
    const float* w1      = (const float*)d_in[9];
    const float* b1      = (const float*)d_in[10];
    const float* w2      = (const float*)d_in[11];
    const float* b2      = (const float*)d_in[12];
    const float* dg      = (const float*)d_in[13];
    const float* db      = (const float*)d_in[14];
    const float* ow      = (const float*)d_in[15];
    const float* ob      = (const float*)d_in[16];
    const float* og      = (const float*)d_in[17];
    const float* obeta   = (const float*)d_in[18];
    const int*   Kp      = (const int*)d_in[20];

    const int Bsz = 128;
    const int S = in_sizes[0] / (Bsz * D);   // N*K+1 = 501
    const int rows = Bsz * S;
    const size_t n_el = (size_t)rows * D;

    float* x  = (float*)d_out;               // activations live in d_out
    float* qb = (float*)d_ws;
    float* kb = qb + n_el;
    float* vb = kb + n_el;

    hipMemcpyAsync(x, samples, n_el * sizeof(float), hipMemcpyDeviceToDevice, stream);

    for (int l = 0; l < 2; ++l) {
        const size_t wo = (size_t)l * D * D;
        qkv_kernel<<<rows, 256, 0, stream>>>(x, Wq + wo, Wk + wo, Wv + wo, qb, kb, vb);
        attn_kernel<<<dim3(S, H, Bsz), 256, 0, stream>>>(qb, kb, vb,
                                                         attn_w + (size_t)l * H * 6, Kp,
                                                         qb /*out aliases q*/, S);
        fc_res_ln_kernel<<<rows, 256, 0, stream>>>(qb, fc_w + wo, fc_b + (size_t)l * D,
                                                   x, mha_g + (size_t)l * D, mha_b + (size_t)l * D, x);
        ffn_ln_kernel<<<rows, 256, 0, stream>>>(w1 + wo, b1 + (size_t)l * D,
                                                w2 + wo, b2 + (size_t)l * D,
                                                x, dg + (size_t)l * D, db + (size_t)l * D);
    }
    fc_res_ln_kernel<<<rows, 256, 0, stream>>>(x, ow, ob, samples, og, obeta, x);
}

// Round 2
// 5122.252 us; speedup vs baseline: 4.5421x; 4.5421x over previous
//
#include <hip/hip_runtime.h>
#include <cstdint>
#include <cstddef>
#include <cmath>

#define D 256
#define H 4
#define LN_EPS 1e-5f
#define SPAD 512

typedef __attribute__((ext_vector_type(8))) short short8;
typedef __attribute__((ext_vector_type(4))) float f32x4;

static __device__ __forceinline__ short f2bf(float f) {
    union { float f; unsigned u; } a; a.f = f;
    unsigned r = a.u + 0x7fffu + ((a.u >> 16) & 1u);
    return (short)(r >> 16);
}

// ---------------- QKV projection: 8 rows per block, emits bf16 MFMA-layouts ----------------
__global__ __launch_bounds__(256)
void qkv_kernel(const float* __restrict__ x,
                const float* __restrict__ Wq, const float* __restrict__ Wk,
                const float* __restrict__ Wv,
                short* __restrict__ Qb, short* __restrict__ Kb,
                short* __restrict__ Vt, int S)
{
    const int r0 = blockIdx.x * 8;
    const int j = threadIdx.x;
    __shared__ float xs[8][D];
    #pragma unroll
    for (int r = 0; r < 8; ++r) xs[r][j] = x[(size_t)(r0 + r) * D + j];
    __syncthreads();
    float aq[8], ak[8], av[8];
    #pragma unroll
    for (int r = 0; r < 8; ++r) { aq[r] = 0.f; ak[r] = 0.f; av[r] = 0.f; }
    for (int i = 0; i < D; i += 4) {
        f32x4 xr[8];
        #pragma unroll
        for (int r = 0; r < 8; ++r) xr[r] = *(const f32x4*)&xs[r][i];
        #pragma unroll
        for (int u = 0; u < 4; ++u) {
            const float wq = Wq[(i + u) * D + j];
            const float wk = Wk[(i + u) * D + j];
            const float wv = Wv[(i + u) * D + j];
            #pragma unroll
            for (int r = 0; r < 8; ++r) {
                const float xv = xr[r][u];
                aq[r] = fmaf(xv, wq, aq[r]);
                ak[r] = fmaf(xv, wk, ak[r]);
                av[r] = fmaf(xv, wv, av[r]);
            }
        }
    }
    const int h = j >> 6, dim = j & 63;
    #pragma unroll
    for (int r = 0; r < 8; ++r) {
        const int row = r0 + r;
        const int b = row / S, s = row - b * S;
        const size_t bh = (size_t)(b * H + h);
        const size_t qk = (bh * S + s) * 64 + dim;
        Qb[qk] = f2bf(aq[r] * 0.125f);       // fold 1/sqrt(DK) into Q
        Kb[qk] = f2bf(ak[r]);
        Vt[(bh * 64 + dim) * SPAD + s] = f2bf(av[r]);
    }
}

// ---------------- MFMA flash attention: block = (qtile16, h, b), 4 waves split keys ----------------
__global__ __launch_bounds__(256)
void attn_kernel(const short* __restrict__ Qb, const short* __restrict__ Kb,
                 const short* __restrict__ Vt,
                 const float* __restrict__ attn_w_l, const int* __restrict__ Kp,
                 float* __restrict__ out, int S)
{
    const int q0 = blockIdx.x << 4;
    const int h = blockIdx.y, b = blockIdx.z;
    const int bh = b * H + h;
    const int tid = threadIdx.x;
    const int wave = tid >> 6, lane = tid & 63;
    const int l16 = lane & 15, quad = lane >> 4;
    const int NK = S - 1;
    const int Kc = Kp[0];

    __shared__ float gsh[6];
    __shared__ __align__(16) short Pb[4][16][40];   // per-wave P chunk, C-layout -> A-layout
    __shared__ float Of[4][16][64];                 // per-wave partial O
    __shared__ float Ml[4][2][16];                  // per-wave m,l per row

    if (tid < 6) gsh[tid] = tanhf(attn_w_l[h * 6 + tid]);
    __syncthreads();
    const float g0 = gsh[0], g1 = gsh[1], g2 = gsh[2],
                g3 = gsh[3], g4 = gsh[4], g5 = gsh[5];

    int qg[4], qcls[4];
    #pragma unroll
    for (int r = 0; r < 4; ++r) {
        qg[r] = q0 + quad * 4 + r;                  // C-layout row of reg r
        qcls[r] = (qg[r] < NK) ? (qg[r] / Kc) : -1;
    }

    // Q A-fragments (two K=32 halves), loaded once
    const size_t qrow = ((size_t)bh * S + min(q0 + l16, S - 1)) * 64;
    const short8 aq0 = *(const short8*)(Qb + qrow + quad * 8);
    const short8 aq1 = *(const short8*)(Qb + qrow + 32 + quad * 8);

    f32x4 O[4];
    #pragma unroll
    for (int dt = 0; dt < 4; ++dt) O[dt] = (f32x4){0.f, 0.f, 0.f, 0.f};
    float mr[4], lr[4];
    #pragma unroll
    for (int r = 0; r < 4; ++r) { mr[r] = -INFINITY; lr[r] = 0.f; }

    const short* Vbh = Vt + (size_t)bh * 64 * SPAD;
    const int nchunk = (S + 31) >> 5;
    for (int c = wave; c < nchunk; c += 4) {
        const int kbase = c << 5;
        const int key0 = kbase + l16;
        const int key1 = key0 + 16;
        const size_t kr0 = ((size_t)bh * S + min(key0, S - 1)) * 64;
        const size_t kr1 = ((size_t)bh * S + min(key1, S - 1)) * 64;
        const short8 kb00 = *(const short8*)(Kb + kr0 + quad * 8);
        const short8 kb01 = *(const short8*)(Kb + kr0 + 32 + quad * 8);
        const short8 kb10 = *(const short8*)(Kb + kr1 + quad * 8);
        const short8 kb11 = *(const short8*)(Kb + kr1 + 32 + quad * 8);
        f32x4 s0 = (f32x4){0.f, 0.f, 0.f, 0.f}, s1 = (f32x4){0.f, 0.f, 0.f, 0.f};
        s0 = __builtin_amdgcn_mfma_f32_16x16x32_bf16(aq0, kb00, s0, 0, 0, 0);
        s0 = __builtin_amdgcn_mfma_f32_16x16x32_bf16(aq1, kb01, s0, 0, 0, 0);
        s1 = __builtin_amdgcn_mfma_f32_16x16x32_bf16(aq0, kb10, s1, 0, 0, 0);
        s1 = __builtin_amdgcn_mfma_f32_16x16x32_bf16(aq1, kb11, s1, 0, 0, 0);
        const bool v0 = key0 < S, v1 = key1 < S;

        float sm0[4], sm1[4], cm[4];
        #pragma unroll
        for (int r = 0; r < 4; ++r) {
            sm0[r] = v0 ? s0[r] : -INFINITY;
            sm1[r] = v1 ? s1[r] : -INFINITY;
            cm[r] = fmaxf(sm0[r], sm1[r]);
        }
        #pragma unroll
        for (int m = 1; m < 16; m <<= 1) {
            #pragma unroll
            for (int r = 0; r < 4; ++r) cm[r] = fmaxf(cm[r], __shfl_xor(cm[r], m, 64));
        }
        const int kc0 = key0 / Kc;
        const int kc1 = key1 / Kc;
        float e0[4], e1[4], cs[4], alpha[4];
        #pragma unroll
        for (int r = 0; r < 4; ++r) {
            const float mnew = fmaxf(mr[r], cm[r]);
            alpha[r] = __expf(mr[r] - mnew);
            mr[r] = mnew;
            e0[r] = v0 ? __expf(sm0[r] - mnew) : 0.f;
            e1[r] = v1 ? __expf(sm1[r] - mnew) : 0.f;
            cs[r] = e0[r] + e1[r];
        }
        #pragma unroll
        for (int m = 1; m < 16; m <<= 1) {
            #pragma unroll
            for (int r = 0; r < 4; ++r) cs[r] += __shfl_xor(cs[r], m, 64);
        }
        #pragma unroll
        for (int r = 0; r < 4; ++r) {
            lr[r] = lr[r] * alpha[r] + cs[r];
            #pragma unroll
            for (int dt = 0; dt < 4; ++dt) O[dt][r] *= alpha[r];
        }
        // post-softmax tanh gate (denominator stays ungated, per reference), pack bf16
        #pragma unroll
        for (int r = 0; r < 4; ++r) {
            float p0, p1;
            if (qg[r] < NK) {
                const float gg0 = (key0 == NK) ? g3 : ((key0 == qg[r]) ? g0 : ((kc0 == qcls[r]) ? g1 : g2));
                const float gg1 = (key1 == NK) ? g3 : ((key1 == qg[r]) ? g0 : ((kc1 == qcls[r]) ? g1 : g2));
                p0 = e0[r] * gg0; p1 = e1[r] * gg1;
            } else {
                p0 = e0[r] * ((key0 < NK) ? g4 : g5);
                p1 = e1[r] * ((key1 < NK) ? g4 : g5);
            }
            const int row = quad * 4 + r;
            Pb[wave][row][l16] = f2bf(p0);
            Pb[wave][row][16 + l16] = f2bf(p1);
        }
        // C-layout -> A-layout via per-wave LDS round trip
        const short8 ap = *(const short8*)(&Pb[wave][l16][quad * 8]);
        #pragma unroll
        for (int dt = 0; dt < 4; ++dt) {
            const short8 vb = *(const short8*)(Vbh + (size_t)(dt * 16 + l16) * SPAD + kbase + quad * 8);
            O[dt] = __builtin_amdgcn_mfma_f32_16x16x32_bf16(ap, vb, O[dt], 0, 0, 0);
        }
    }
    // publish per-wave partials
    #pragma unroll
    for (int r = 0; r < 4; ++r) {
        const int row = quad * 4 + r;
        if (l16 == 0) { Ml[wave][0][row] = mr[r]; Ml[wave][1][row] = lr[r]; }
        #pragma unroll
        for (int dt = 0; dt < 4; ++dt) Of[wave][row][dt * 16 + l16] = O[dt][r];
    }
    __syncthreads();
    // flash-combine the 4 waves, write fp32 out
    const int d = tid & 63;
    const int qhi = tid >> 6;
    #pragma unroll
    for (int i = 0; i < 4; ++i) {
        const int q = qhi * 4 + i;
        const int s = q0 + q;
        if (s >= S) continue;
        const float mt = fmaxf(fmaxf(Ml[0][0][q], Ml[1][0][q]), fmaxf(Ml[2][0][q], Ml[3][0][q]));
        float osum = 0.f, lsum = 0.f;
        #pragma unroll
        for (int w = 0; w < 4; ++w) {
            const float f = __expf(Ml[w][0][q] - mt);
            lsum = fmaf(f, Ml[w][1][q], lsum);
            osum = fmaf(f, Of[w][q][d], osum);
        }
        out[((size_t)b * S + s) * D + h * 64 + d] = osum / lsum;
    }
}

// ---------------- FC + residual + LayerNorm: one block per row ----------------
__global__ void fc_res_ln_kernel(const float* __restrict__ tin,
                                 const float* __restrict__ W,
                                 const float* __restrict__ bias,
                                 const float* __restrict__ resid,
                                 const float* __restrict__ gam,
                                 const float* __restrict__ bet,
                                 float* __restrict__ out)
{
    const int row = blockIdx.x, j = threadIdx.x;
    __shared__ float ts[D];
    __shared__ float red[D];
    const size_t base = (size_t)row * D;
    ts[j] = tin[base + j];
    __syncthreads();
    float acc = 0.f;
    #pragma unroll 8
    for (int i = 0; i < D; ++i) acc = fmaf(ts[i], W[i*D + j], acc);
    const float val = acc + bias[j] + resid[base + j];

    red[j] = val; __syncthreads();
    for (int s = 128; s > 0; s >>= 1) { if (j < s) red[j] += red[j + s]; __syncthreads(); }
    const float mu = red[0] * (1.f / D);
    __syncthreads();
    const float dv = val - mu;
    red[j] = dv * dv; __syncthreads();
    for (int s = 128; s > 0; s >>= 1) { if (j < s) red[j] += red[j + s]; __syncthreads(); }
    const float var = red[0] * (1.f / D);
    out[base + j] = dv * rsqrtf(var + LN_EPS) * gam[j] + bet[j];
}

// ---------------- Fused FFN (relu) + residual + LayerNorm, in-place on x ----------------
__global__ void ffn_ln_kernel(const float* __restrict__ W1, const float* __restrict__ b1,
                              const float* __restrict__ W2, const float* __restrict__ b2,
                              float* __restrict__ x,
                              const float* __restrict__ gam, const float* __restrict__ bet)
{
    const int row = blockIdx.x, j = threadIdx.x;
    __shared__ float xs[D];
    __shared__ float hs[D];
    __shared__ float red[D];
    const size_t base = (size_t)row * D;
    const float xv = x[base + j];
    xs[j] = xv;
    __syncthreads();
    float acc = 0.f;
    #pragma unroll 8
    for (int i = 0; i < D; ++i) acc = fmaf(xs[i], W1[i*D + j], acc);
    const float hv = fmaxf(acc + b1[j], 0.f);
    hs[j] = hv;
    __syncthreads();
    acc = 0.f;
    #pragma unroll 8
    for (int i = 0; i < D; ++i) acc = fmaf(hs[i], W2[i*D + j], acc);
    const float val = acc + b2[j] + xv;

    red[j] = val; __syncthreads();
    for (int s = 128; s > 0; s >>= 1) { if (j < s) red[j] += red[j + s]; __syncthreads(); }
    const float mu = red[0] * (1.f / D);
    __syncthreads();
    const float dv = val - mu;
    red[j] = dv * dv; __syncthreads();
    for (int s = 128; s > 0; s >>= 1) { if (j < s) red[j] += red[j + s]; __syncthreads(); }
    const float var = red[0] * (1.f / D);
    x[base + j] = dv * rsqrtf(var + LN_EPS) * gam[j] + bet[j];
}

extern "C" void kernel_launch(void* const* d_in, const int* in_sizes, int n_in,
                              void* d_out, int out_size, void* d_ws, size_t ws_size,
                              hipStream_t stream)
{
    const float* samples = (const float*)d_in[0];
    const float* Wq      = (const float*)d_in[1];
    const float* Wk      = (const float*)d_in[2];
    const float* Wv      = (const float*)d_in[3];
    const float* attn_w  = (const float*)d_in[4];
    const float* fc_w    = (const float*)d_in[5];
    const float* fc_b    = (const float*)d_in[6];
    const float* mha_g   = (const float*)d_in[7];
    const float* mha_b   = (const float*)d_in[8];
    const float* w1      = (const float*)d_in[9];
    const float* b1      = (const float*)d_in[10];
    const float* w2      = (const float*)d_in[11];
    const float* b2      = (const float*)d_in[12];
    const float* dg      = (const float*)d_in[13];
    const float* db      = (const float*)d_in[14];
    const float* ow      = (const float*)d_in[15];
    const float* ob      = (const float*)d_in[16];
    const float* og      = (const float*)d_in[17];
    const float* obeta   = (const float*)d_in[18];
    const int*   Kp      = (const int*)d_in[20];

    const int Bsz = 128;
    const int S = in_sizes[0] / (Bsz * D);   // N*K+1 = 501
    const int rows = Bsz * S;
    const size_t n_el = (size_t)rows * D;

    float* x  = (float*)d_out;               // activations live in d_out
    float* ao = (float*)d_ws;                // attention output fp32 [B,S,D]
    short* Qb = (short*)(ao + n_el);         // bf16 [B,H,S,64]
    short* Kb = Qb + n_el;                   // bf16 [B,H,S,64]
    short* Vt = Kb + n_el;                   // bf16 [B,H,64,SPAD]

    hipMemcpyAsync(x, samples, n_el * sizeof(float), hipMemcpyDeviceToDevice, stream);

    for (int l = 0; l < 2; ++l) {
        const size_t wo = (size_t)l * D * D;
        qkv_kernel<<<rows / 8, 256, 0, stream>>>(x, Wq + wo, Wk + wo, Wv + wo,
                                                 Qb, Kb, Vt, S);
        attn_kernel<<<dim3((S + 15) / 16, H, Bsz), 256, 0, stream>>>(Qb, Kb, Vt,
                                                 attn_w + (size_t)l * H * 6, Kp, ao, S);
        fc_res_ln_kernel<<<rows, 256, 0, stream>>>(ao, fc_w + wo, fc_b + (size_t)l * D,
                                                   x, mha_g + (size_t)l * D, mha_b + (size_t)l * D, x);
        ffn_ln_kernel<<<rows, 256, 0, stream>>>(w1 + wo, b1 + (size_t)l * D,
                                                w2 + wo, b2 + (size_t)l * D,
                                                x, dg + (size_t)l * D, db + (size_t)l * D);
    }
    fc_res_ln_kernel<<<rows, 256, 0, stream>>>(x, ow, ob, samples, og, obeta, x);
}

// Round 3
// 1735.426 us; speedup vs baseline: 13.4065x; 2.9516x over previous
//
#include <hip/hip_runtime.h>
#include <cstdint>
#include <cstddef>
#include <cmath>

#define D 256
#define H 4
#define LN_EPS 1e-5f
#define SPAD 512
#define NMAT 13

typedef __attribute__((ext_vector_type(8))) short short8;
typedef __attribute__((ext_vector_type(4))) short short4v;
typedef __attribute__((ext_vector_type(4))) float f32x4;

static __device__ __forceinline__ short f2bf(float f) {
    union { float f; unsigned u; } a; a.f = f;
    unsigned r = a.u + 0x7fffu + ((a.u >> 16) & 1u);
    return (short)(r >> 16);
}

// ---------- pack fp32 W[k][n] -> bf16 Bt[n][k] (MFMA B-fragment friendly) ----------
struct PackArgs { const float* src[NMAT]; float scale[NMAT]; short* dst; };

__global__ __launch_bounds__(256)
void pack_kernel(PackArgs pa)
{
    const int mat = blockIdx.y;
    const int el = blockIdx.x * 256 + threadIdx.x;   // 0..65535
    const int n = el & 255, k = el >> 8;
    pa.dst[(size_t)mat * 65536 + (size_t)n * 256 + k] =
        f2bf(pa.src[mat][(size_t)k * 256 + n] * pa.scale[mat]);
}

// ---------- fp32 -> bf16 cast ----------
__global__ __launch_bounds__(256)
void cast_kernel(const float* __restrict__ x, short* __restrict__ xb, long n)
{
    const long i = ((long)blockIdx.x * 256 + threadIdx.x) * 4;
    if (i >= n) return;
    const f32x4 v = *(const f32x4*)(x + i);
    short4v o;
    o.x = f2bf(v.x); o.y = f2bf(v.y); o.z = f2bf(v.z); o.w = f2bf(v.w);
    *(short4v*)(xb + i) = o;
}

// ---------- shared MFMA mainloop: 16 rows x 256 cols per wave, K=256 ----------
static __device__ __forceinline__ void gemm_tile(const short* __restrict__ A,
                                                 const short* __restrict__ Bt,
                                                 int rowA, int l16, int quad,
                                                 f32x4 (&acc)[16])
{
    const short* Ar = A + (size_t)rowA * D + quad * 8;
    const short* Bl = Bt + (size_t)l16 * D + quad * 8;
    #pragma unroll
    for (int nt = 0; nt < 16; ++nt) acc[nt] = (f32x4){0.f, 0.f, 0.f, 0.f};
    #pragma unroll
    for (int kc = 0; kc < 8; ++kc) {
        const short8 af = *(const short8*)(Ar + kc * 32);
        #pragma unroll
        for (int nt = 0; nt < 16; ++nt) {
            const short8 bf = *(const short8*)(Bl + (size_t)nt * 16 * D + kc * 32);
            acc[nt] = __builtin_amdgcn_mfma_f32_16x16x32_bf16(af, bf, acc[nt], 0, 0, 0);
        }
    }
}

// ---------- GEMM + bias + residual + LayerNorm, writes fp32 + bf16 ----------
__global__ __launch_bounds__(256)
void gemm_res_ln_kernel(const short* __restrict__ A, const short* __restrict__ Bt,
                        const float* __restrict__ bias, const float* __restrict__ resid,
                        const float* __restrict__ gam, const float* __restrict__ bet,
                        float* __restrict__ xout, short* __restrict__ xbout)
{
    const int tid = threadIdx.x, wave = tid >> 6, lane = tid & 63;
    const int l16 = lane & 15, quad = lane >> 4;
    const int row0 = blockIdx.x * 64 + wave * 16;
    f32x4 acc[16];
    gemm_tile(A, Bt, row0 + l16, l16, quad, acc);

    #pragma unroll
    for (int nt = 0; nt < 16; ++nt) {
        const int col = nt * 16 + l16;
        const float bl = bias[col];
        #pragma unroll
        for (int r = 0; r < 4; ++r)
            acc[nt][r] += bl + resid[(size_t)(row0 + quad * 4 + r) * D + col];
    }
    float mu[4], rstd[4];
    #pragma unroll
    for (int r = 0; r < 4; ++r) {
        float s = 0.f;
        #pragma unroll
        for (int nt = 0; nt < 16; ++nt) s += acc[nt][r];
        s += __shfl_xor(s, 1, 64); s += __shfl_xor(s, 2, 64);
        s += __shfl_xor(s, 4, 64); s += __shfl_xor(s, 8, 64);
        mu[r] = s * (1.f / D);
        float q = 0.f;
        #pragma unroll
        for (int nt = 0; nt < 16; ++nt) { const float d = acc[nt][r] - mu[r]; q = fmaf(d, d, q); }
        q += __shfl_xor(q, 1, 64); q += __shfl_xor(q, 2, 64);
        q += __shfl_xor(q, 4, 64); q += __shfl_xor(q, 8, 64);
        rstd[r] = rsqrtf(q * (1.f / D) + LN_EPS);
    }
    #pragma unroll
    for (int nt = 0; nt < 16; ++nt) {
        const int col = nt * 16 + l16;
        const float g = gam[col], be = bet[col];
        #pragma unroll
        for (int r = 0; r < 4; ++r) {
            const size_t idx = (size_t)(row0 + quad * 4 + r) * D + col;
            const float o = (acc[nt][r] - mu[r]) * rstd[r] * g + be;
            xout[idx] = o;
            xbout[idx] = f2bf(o);
        }
    }
}

// ---------- GEMM + bias + relu -> bf16 ----------
__global__ __launch_bounds__(256)
void gemm_relu_kernel(const short* __restrict__ A, const short* __restrict__ Bt,
                      const float* __restrict__ bias, short* __restrict__ hb)
{
    const int tid = threadIdx.x, wave = tid >> 6, lane = tid & 63;
    const int l16 = lane & 15, quad = lane >> 4;
    const int row0 = blockIdx.x * 64 + wave * 16;
    f32x4 acc[16];
    gemm_tile(A, Bt, row0 + l16, l16, quad, acc);
    #pragma unroll
    for (int nt = 0; nt < 16; ++nt) {
        const int col = nt * 16 + l16;
        const float bl = bias[col];
        #pragma unroll
        for (int r = 0; r < 4; ++r)
            hb[(size_t)(row0 + quad * 4 + r) * D + col] = f2bf(fmaxf(acc[nt][r] + bl, 0.f));
    }
}

// ---------- QKV: three GEMMs, writes Q,K (scaled at pack) + V^T layouts ----------
__global__ __launch_bounds__(256)
void qkv_gemm_kernel(const short* __restrict__ A, const short* __restrict__ Wt,
                     short* __restrict__ Qb, short* __restrict__ Kb,
                     short* __restrict__ Vt, int S)
{
    const int tid = threadIdx.x, wave = tid >> 6, lane = tid & 63;
    const int l16 = lane & 15, quad = lane >> 4;
    const int row0 = blockIdx.x * 64 + wave * 16;
    int bb[4], ss[4];
    #pragma unroll
    for (int r = 0; r < 4; ++r) {
        const int row = row0 + quad * 4 + r;
        bb[r] = row / S; ss[r] = row - bb[r] * S;
    }
    #pragma unroll 1
    for (int m = 0; m < 3; ++m) {
        f32x4 acc[16];
        gemm_tile(A, Wt + (size_t)m * 65536, row0 + l16, l16, quad, acc);
        #pragma unroll
        for (int nt = 0; nt < 16; ++nt) {
            const int col = nt * 16 + l16, h = col >> 6, dim = col & 63;
            #pragma unroll
            for (int r = 0; r < 4; ++r) {
                const int bh = bb[r] * H + h;
                const short v = f2bf(acc[nt][r]);
                if (m == 0)      Qb[((size_t)bh * S + ss[r]) * 64 + dim] = v;
                else if (m == 1) Kb[((size_t)bh * S + ss[r]) * 64 + dim] = v;
                else             Vt[((size_t)bh * 64 + dim) * SPAD + ss[r]] = v;
            }
        }
    }
}

// ---------------- MFMA flash attention (round-2, now emits bf16) ----------------
__global__ __launch_bounds__(256)
void attn_kernel(const short* __restrict__ Qb, const short* __restrict__ Kb,
                 const short* __restrict__ Vt,
                 const float* __restrict__ attn_w_l, const int* __restrict__ Kp,
                 short* __restrict__ out, int S)
{
    const int q0 = blockIdx.x << 4;
    const int h = blockIdx.y, b = blockIdx.z;
    const int bh = b * H + h;
    const int tid = threadIdx.x;
    const int wave = tid >> 6, lane = tid & 63;
    const int l16 = lane & 15, quad = lane >> 4;
    const int NK = S - 1;
    const int Kc = Kp[0];

    __shared__ float gsh[6];
    __shared__ __align__(16) short Pb[4][16][40];
    __shared__ float Of[4][16][64];
    __shared__ float Ml[4][2][16];

    if (tid < 6) gsh[tid] = tanhf(attn_w_l[h * 6 + tid]);
    __syncthreads();
    const float g0 = gsh[0], g1 = gsh[1], g2 = gsh[2],
                g3 = gsh[3], g4 = gsh[4], g5 = gsh[5];

    int qg[4], qcls[4];
    #pragma unroll
    for (int r = 0; r < 4; ++r) {
        qg[r] = q0 + quad * 4 + r;
        qcls[r] = (qg[r] < NK) ? (qg[r] / Kc) : -1;
    }

    const size_t qrow = ((size_t)bh * S + min(q0 + l16, S - 1)) * 64;
    const short8 aq0 = *(const short8*)(Qb + qrow + quad * 8);
    const short8 aq1 = *(const short8*)(Qb + qrow + 32 + quad * 8);

    f32x4 O[4];
    #pragma unroll
    for (int dt = 0; dt < 4; ++dt) O[dt] = (f32x4){0.f, 0.f, 0.f, 0.f};
    float mr[4], lr[4];
    #pragma unroll
    for (int r = 0; r < 4; ++r) { mr[r] = -INFINITY; lr[r] = 0.f; }

    const short* Vbh = Vt + (size_t)bh * 64 * SPAD;
    const int nchunk = (S + 31) >> 5;
    for (int c = wave; c < nchunk; c += 4) {
        const int kbase = c << 5;
        const int key0 = kbase + l16;
        const int key1 = key0 + 16;
        const size_t kr0 = ((size_t)bh * S + min(key0, S - 1)) * 64;
        const size_t kr1 = ((size_t)bh * S + min(key1, S - 1)) * 64;
        const short8 kb00 = *(const short8*)(Kb + kr0 + quad * 8);
        const short8 kb01 = *(const short8*)(Kb + kr0 + 32 + quad * 8);
        const short8 kb10 = *(const short8*)(Kb + kr1 + quad * 8);
        const short8 kb11 = *(const short8*)(Kb + kr1 + 32 + quad * 8);
        f32x4 s0 = (f32x4){0.f, 0.f, 0.f, 0.f}, s1 = (f32x4){0.f, 0.f, 0.f, 0.f};
        s0 = __builtin_amdgcn_mfma_f32_16x16x32_bf16(aq0, kb00, s0, 0, 0, 0);
        s0 = __builtin_amdgcn_mfma_f32_16x16x32_bf16(aq1, kb01, s0, 0, 0, 0);
        s1 = __builtin_amdgcn_mfma_f32_16x16x32_bf16(aq0, kb10, s1, 0, 0, 0);
        s1 = __builtin_amdgcn_mfma_f32_16x16x32_bf16(aq1, kb11, s1, 0, 0, 0);
        const bool v0 = key0 < S, v1 = key1 < S;

        float sm0[4], sm1[4], cm[4];
        #pragma unroll
        for (int r = 0; r < 4; ++r) {
            sm0[r] = v0 ? s0[r] : -INFINITY;
            sm1[r] = v1 ? s1[r] : -INFINITY;
            cm[r] = fmaxf(sm0[r], sm1[r]);
        }
        #pragma unroll
        for (int m = 1; m < 16; m <<= 1) {
            #pragma unroll
            for (int r = 0; r < 4; ++r) cm[r] = fmaxf(cm[r], __shfl_xor(cm[r], m, 64));
        }
        const int kc0 = key0 / Kc;
        const int kc1 = key1 / Kc;
        float e0[4], e1[4], cs[4], alpha[4];
        #pragma unroll
        for (int r = 0; r < 4; ++r) {
            const float mnew = fmaxf(mr[r], cm[r]);
            alpha[r] = __expf(mr[r] - mnew);
            mr[r] = mnew;
            e0[r] = v0 ? __expf(sm0[r] - mnew) : 0.f;
            e1[r] = v1 ? __expf(sm1[r] - mnew) : 0.f;
            cs[r] = e0[r] + e1[r];
        }
        #pragma unroll
        for (int m = 1; m < 16; m <<= 1) {
            #pragma unroll
            for (int r = 0; r < 4; ++r) cs[r] += __shfl_xor(cs[r], m, 64);
        }
        #pragma unroll
        for (int r = 0; r < 4; ++r) {
            lr[r] = lr[r] * alpha[r] + cs[r];
            #pragma unroll
            for (int dt = 0; dt < 4; ++dt) O[dt][r] *= alpha[r];
        }
        #pragma unroll
        for (int r = 0; r < 4; ++r) {
            float p0, p1;
            if (qg[r] < NK) {
                const float gg0 = (key0 == NK) ? g3 : ((key0 == qg[r]) ? g0 : ((kc0 == qcls[r]) ? g1 : g2));
                const float gg1 = (key1 == NK) ? g3 : ((key1 == qg[r]) ? g0 : ((kc1 == qcls[r]) ? g1 : g2));
                p0 = e0[r] * gg0; p1 = e1[r] * gg1;
            } else {
                p0 = e0[r] * ((key0 < NK) ? g4 : g5);
                p1 = e1[r] * ((key1 < NK) ? g4 : g5);
            }
            const int row = quad * 4 + r;
            Pb[wave][row][l16] = f2bf(p0);
            Pb[wave][row][16 + l16] = f2bf(p1);
        }
        const short8 ap = *(const short8*)(&Pb[wave][l16][quad * 8]);
        #pragma unroll
        for (int dt = 0; dt < 4; ++dt) {
            const short8 vb = *(const short8*)(Vbh + (size_t)(dt * 16 + l16) * SPAD + kbase + quad * 8);
            O[dt] = __builtin_amdgcn_mfma_f32_16x16x32_bf16(ap, vb, O[dt], 0, 0, 0);
        }
    }
    #pragma unroll
    for (int r = 0; r < 4; ++r) {
        const int row = quad * 4 + r;
        if (l16 == 0) { Ml[wave][0][row] = mr[r]; Ml[wave][1][row] = lr[r]; }
        #pragma unroll
        for (int dt = 0; dt < 4; ++dt) Of[wave][row][dt * 16 + l16] = O[dt][r];
    }
    __syncthreads();
    const int d = tid & 63;
    const int qhi = tid >> 6;
    #pragma unroll
    for (int i = 0; i < 4; ++i) {
        const int q = qhi * 4 + i;
        const int s = q0 + q;
        if (s >= S) continue;
        const float mt = fmaxf(fmaxf(Ml[0][0][q], Ml[1][0][q]), fmaxf(Ml[2][0][q], Ml[3][0][q]));
        float osum = 0.f, lsum = 0.f;
        #pragma unroll
        for (int w = 0; w < 4; ++w) {
            const float f = __expf(Ml[w][0][q] - mt);
            lsum = fmaf(f, Ml[w][1][q], lsum);
            osum = fmaf(f, Of[w][q][d], osum);
        }
        out[((size_t)b * S + s) * D + h * 64 + d] = f2bf(osum / lsum);
    }
}

extern "C" void kernel_launch(void* const* d_in, const int* in_sizes, int n_in,
                              void* d_out, int out_size, void* d_ws, size_t ws_size,
                              hipStream_t stream)
{
    const float* samples = (const float*)d_in[0];
    const float* Wq      = (const float*)d_in[1];
    const float* Wk      = (const float*)d_in[2];
    const float* Wv      = (const float*)d_in[3];
    const float* attn_w  = (const float*)d_in[4];
    const float* fc_w    = (const float*)d_in[5];
    const float* fc_b    = (const float*)d_in[6];
    const float* mha_g   = (const float*)d_in[7];
    const float* mha_b   = (const float*)d_in[8];
    const float* w1      = (const float*)d_in[9];
    const float* b1      = (const float*)d_in[10];
    const float* w2      = (const float*)d_in[11];
    const float* b2      = (const float*)d_in[12];
    const float* dg      = (const float*)d_in[13];
    const float* db      = (const float*)d_in[14];
    const float* ow      = (const float*)d_in[15];
    const float* ob      = (const float*)d_in[16];
    const float* og      = (const float*)d_in[17];
    const float* obeta   = (const float*)d_in[18];
    const int*   Kp      = (const int*)d_in[20];

    const int Bsz = 128;
    const int S = in_sizes[0] / (Bsz * D);   // 501
    const int rows = Bsz * S;                // 64128 = 1002*64
    const size_t n_el = (size_t)rows * D;

    float* x   = (float*)d_out;
    short* xb  = (short*)d_ws;               // bf16 activations [rows][D]
    short* aob = xb + n_el;                  // attn out bf16; later reused as hb
    short* hb  = aob;
    short* Qb  = aob + n_el;
    short* Kb  = Qb + n_el;
    short* Vt  = Kb + n_el;                  // [B*H][64][SPAD]
    short* wts = Vt + (size_t)Bsz * H * 64 * SPAD;

    // pack all weights -> bf16 Bt[n][k]; Q weights pre-scaled by 1/sqrt(DK)
    PackArgs pa;
    for (int l = 0; l < 2; ++l) {
        const size_t wo = (size_t)l * 65536;
        pa.src[l*6 + 0] = Wq + wo;   pa.scale[l*6 + 0] = 0.125f;
        pa.src[l*6 + 1] = Wk + wo;   pa.scale[l*6 + 1] = 1.f;
        pa.src[l*6 + 2] = Wv + wo;   pa.scale[l*6 + 2] = 1.f;
        pa.src[l*6 + 3] = fc_w + wo; pa.scale[l*6 + 3] = 1.f;
        pa.src[l*6 + 4] = w1 + wo;   pa.scale[l*6 + 4] = 1.f;
        pa.src[l*6 + 5] = w2 + wo;   pa.scale[l*6 + 5] = 1.f;
    }
    pa.src[12] = ow; pa.scale[12] = 1.f;
    pa.dst = wts;
    pack_kernel<<<dim3(256, NMAT), 256, 0, stream>>>(pa);

    hipMemcpyAsync(x, samples, n_el * sizeof(float), hipMemcpyDeviceToDevice, stream);
    cast_kernel<<<(int)((n_el / 4 + 255) / 256), 256, 0, stream>>>(samples, xb, (long)n_el);

    const int gblocks = rows / 64;           // 1002
    for (int l = 0; l < 2; ++l) {
        short* wl = wts + (size_t)l * 6 * 65536;
        qkv_gemm_kernel<<<gblocks, 256, 0, stream>>>(xb, wl, Qb, Kb, Vt, S);
        attn_kernel<<<dim3((S + 15) / 16, H, Bsz), 256, 0, stream>>>(Qb, Kb, Vt,
                                              attn_w + (size_t)l * H * 6, Kp, aob, S);
        gemm_res_ln_kernel<<<gblocks, 256, 0, stream>>>(aob, wl + 3 * 65536,
                                              fc_b + (size_t)l * D, x,
                                              mha_g + (size_t)l * D, mha_b + (size_t)l * D,
                                              x, xb);
        gemm_relu_kernel<<<gblocks, 256, 0, stream>>>(xb, wl + 4 * 65536,
                                              b1 + (size_t)l * D, hb);
        gemm_res_ln_kernel<<<gblocks, 256, 0, stream>>>(hb, wl + 5 * 65536,
                                              b2 + (size_t)l * D, x,
                                              dg + (size_t)l * D, db + (size_t)l * D,
                                              x, xb);
    }
    gemm_res_ln_kernel<<<gblocks, 256, 0, stream>>>(xb, wts + 12 * 65536,
                                              ob, samples, og, obeta, x, xb);
}